// Round 1
// baseline (285.588 us; speedup 1.0000x reference)
//
#include <hip/hip_runtime.h>
#include <hip/hip_bf16.h>

#define THRESH 0.5f

// ---------------- Kernel 1a: per-anchor match (argmax over boxes) + zero hists/scalars
__global__ void k_match(const float* __restrict__ boxes, const float* __restrict__ dflt,
                        unsigned* __restrict__ match, unsigned* __restrict__ zeroArea,
                        int nzero, int B, int A, int M, int chunks) {
    if (blockIdx.x == 0) {
        for (int i = threadIdx.x; i < nzero; i += blockDim.x) zeroArea[i] = 0u;
    }
    __shared__ float bx[128 * 4];
    __shared__ float barea[128];
    int b = blockIdx.x / chunks;
    int a = (blockIdx.x % chunks) * 256 + threadIdx.x;
    for (int j = threadIdx.x; j < M * 4; j += blockDim.x)
        bx[j] = boxes[(size_t)b * M * 4 + j];
    __syncthreads();
    if (threadIdx.x < M) {
        float x1 = bx[threadIdx.x*4], y1 = bx[threadIdx.x*4+1];
        float x2 = bx[threadIdx.x*4+2], y2 = bx[threadIdx.x*4+3];
        barea[threadIdx.x] = (x2 - x1) * (y2 - y1);
    }
    __syncthreads();
    if (a >= A) return;
    const float* dp = dflt + (size_t)a * 4;
    float dcx = dp[0], dcy = dp[1], dw = dp[2], dh = dp[3];
    float dx1 = dcx - dw*0.5f, dy1 = dcy - dh*0.5f;
    float dx2 = dcx + dw*0.5f, dy2 = dcy + dh*0.5f;
    float darea = (dx2 - dx1) * (dy2 - dy1);
    float best = -1.0f; int bi = 0;
    for (int m = 0; m < M; ++m) {
        float x1 = bx[m*4], y1 = bx[m*4+1], x2 = bx[m*4+2], y2 = bx[m*4+3];
        float lx = fmaxf(x1, dx1), ly = fmaxf(y1, dy1);
        float rx = fminf(x2, dx2), ry = fminf(y2, dy2);
        float w = fmaxf(rx - lx, 0.f), h = fmaxf(ry - ly, 0.f);
        float inter = w * h;
        float iou = inter / (barea[m] + darea - inter);
        if (iou > best) { best = iou; bi = m; }
    }
    unsigned fl = (best >= THRESH) ? (1u << 30) : 0u;
    match[(size_t)b * A + a] = (unsigned)bi | fl;
}

// ---------------- Kernel 1b: per-box best anchor, override via atomicMax (last box wins)
__global__ void k_bestanchor(const float* __restrict__ boxes, const float* __restrict__ dflt,
                             unsigned* __restrict__ match, int B, int A, int M) {
    int wid = (blockIdx.x * blockDim.x + threadIdx.x) >> 6;
    int lane = threadIdx.x & 63;
    int b = wid / M, m = wid % M;
    if (b >= B) return;
    const float* bp = boxes + ((size_t)b * M + m) * 4;
    float x1 = bp[0], y1 = bp[1], x2 = bp[2], y2 = bp[3];
    float ba = (x2 - x1) * (y2 - y1);
    float best = -1.0f; int bi = 0;
    for (int a = lane; a < A; a += 64) {
        const float* dp = dflt + (size_t)a * 4;
        float dcx = dp[0], dcy = dp[1], dw = dp[2], dh = dp[3];
        float dx1 = dcx - dw*0.5f, dy1 = dcy - dh*0.5f;
        float dx2 = dcx + dw*0.5f, dy2 = dcy + dh*0.5f;
        float darea = (dx2 - dx1) * (dy2 - dy1);
        float lx = fmaxf(x1, dx1), ly = fmaxf(y1, dy1);
        float rx = fminf(x2, dx2), ry = fminf(y2, dy2);
        float w = fmaxf(rx - lx, 0.f), h = fmaxf(ry - ly, 0.f);
        float inter = w * h;
        float iou = inter / (ba + darea - inter);
        if (iou > best) { best = iou; bi = a; }
    }
    for (int off = 32; off > 0; off >>= 1) {
        float ov = __shfl_down(best, off, 64);
        int   oi = __shfl_down(bi, off, 64);
        if (ov > best || (ov == best && oi < bi)) { best = ov; bi = oi; }
    }
    if (lane == 0)
        atomicMax(&match[(size_t)b * A + bi], 0x80000000u | (unsigned)m);
}

// ---------------- Kernel 2: main fused pass
__global__ void k_main(const float* __restrict__ x, const float* __restrict__ y,
                       const float* __restrict__ boxes, const int* __restrict__ labels,
                       const float* __restrict__ dflt, const unsigned* __restrict__ match,
                       float* __restrict__ negv, unsigned* __restrict__ hist1,
                       unsigned* __restrict__ scal, int B, int A, int M, int N) {
    __shared__ unsigned lh[2048];
    for (int j = threadIdx.x; j < 2048; j += blockDim.x) lh[j] = 0u;
    __syncthreads();
    int i = blockIdx.x * blockDim.x + threadIdx.x;
    float l_smooth = 0.f, l_pos = 0.f; int l_cnt = 0;
    if (i < N) {
        int b = i / A, a = i % A;
        unsigned w = match[i];
        int digit = (int)(w & 0xFFFFu);
        int flag = (w & 0x80000000u) ? 1 : (int)((w >> 30) & 1u);
        int lab = labels[b * M + digit];
        int c = flag ? lab : 0;
        bool pos = (c == 1);
        const float* bp = boxes + ((size_t)b * M + digit) * 4;
        float bx1 = bp[0], by1 = bp[1], bx2 = bp[2], by2 = bp[3];
        float cw = bx2 - bx1, ch = by2 - by1;
        float ccx = (bx1 + bx2) * 0.5f, ccy = (by1 + by2) * 0.5f;
        const float* dp = dflt + (size_t)a * 4;
        float dcx = dp[0], dcy = dp[1], dw = dp[2], dh = dp[3];
        float loc[4];
        loc[0] = (ccx - dcx) / (dw * 0.1f);
        loc[1] = (ccy - dcy) / (dh * 0.1f);
        loc[2] = logf(cw / dw) * 5.f;
        loc[3] = logf(ch / dh) * 5.f;
        const float* xp = x + (size_t)i * 4;
        float s = 0.f;
        for (int j = 0; j < 4; ++j) {
            float d = xp[j] - loc[j];
            float ad = fabsf(d);
            s += (ad < 1.f) ? 0.5f * d * d : (ad - 0.5f);
        }
        float y0 = y[(size_t)i * 2], y1v = y[(size_t)i * 2 + 1];
        float mx = fmaxf(y0, y1v);
        float lse = mx + logf(expf(y0 - mx) + expf(y1v - mx));
        float yc = (c == 0) ? y0 : y1v;
        float ent = lse - yc;
        float v = pos ? 0.f : ent;
        negv[i] = v;
        if (pos) { l_smooth = s; l_pos = ent; l_cnt = 1; }
        atomicAdd(&lh[__float_as_uint(v) >> 21], 1u);
    }
    // block reduce (4 waves)
    for (int off = 32; off > 0; off >>= 1) {
        l_smooth += __shfl_down(l_smooth, off, 64);
        l_pos    += __shfl_down(l_pos, off, 64);
        l_cnt    += __shfl_down(l_cnt, off, 64);
    }
    __shared__ float rs[4], rp[4]; __shared__ int rc[4];
    int wv = threadIdx.x >> 6;
    if ((threadIdx.x & 63) == 0) { rs[wv] = l_smooth; rp[wv] = l_pos; rc[wv] = l_cnt; }
    __syncthreads();
    if (threadIdx.x == 0) {
        float ss = rs[0] + rs[1] + rs[2] + rs[3];
        float pp = rp[0] + rp[1] + rp[2] + rp[3];
        int   cc = rc[0] + rc[1] + rc[2] + rc[3];
        if (ss != 0.f) atomicAdd((float*)&scal[2], ss);
        if (pp != 0.f) atomicAdd((float*)&scal[1], pp);
        if (cc)        atomicAdd((int*)&scal[0], cc);
    }
    __syncthreads();
    for (int j = threadIdx.x; j < 2048; j += blockDim.x) {
        unsigned h = lh[j];
        if (h) atomicAdd(&hist1[j], h);
    }
}

// ---------------- scan a histogram, find bin containing k-th largest
__global__ void k_scan(const unsigned* __restrict__ hist, int nbins,
                       unsigned* __restrict__ scal, int kIdx, int bIdx, int kOutIdx) {
    __shared__ unsigned ts[256];
    int t = threadIdx.x;
    int per = nbins / 256;
    unsigned k = scal[kIdx];
    unsigned s = 0;
    for (int j = 0; j < per; ++j) s += hist[t * per + j];
    ts[t] = s;
    __syncthreads();
    for (int off = 1; off < 256; off <<= 1) {
        unsigned add = (t >= off) ? ts[t - off] : 0u;
        __syncthreads();
        ts[t] += add;
        __syncthreads();
    }
    unsigned total = ts[255];
    unsigned P = (t == 0) ? 0u : ts[t - 1];
    for (int j = 0; j < per; ++j) {
        unsigned h = hist[t * per + j];
        P += h;
        unsigned above = total - P;
        if (above < k && k <= above + h) {
            scal[bIdx] = (unsigned)(t * per + j);
            scal[kOutIdx] = k - above;
        }
    }
}

// ---------------- refine histogram at level 2 or 3
__global__ void k_refine(const float* __restrict__ negv, int N,
                         const unsigned* __restrict__ scal,
                         unsigned* __restrict__ histOut, int level) {
    __shared__ unsigned lh[2048];
    int nb = (level == 2) ? 2048 : 1024;
    for (int j = threadIdx.x; j < nb; j += blockDim.x) lh[j] = 0u;
    __syncthreads();
    unsigned prefix = (level == 2) ? scal[3] : ((scal[3] << 11) | scal[5]);
    int shiftm = (level == 2) ? 21 : 10;
    for (int i = blockIdx.x * blockDim.x + threadIdx.x; i < N; i += gridDim.x * blockDim.x) {
        unsigned u = __float_as_uint(negv[i]);
        if ((u >> shiftm) == prefix) {
            unsigned bin = (level == 2) ? ((u >> 10) & 0x7FFu) : (u & 0x3FFu);
            atomicAdd(&lh[bin], 1u);
        }
    }
    __syncthreads();
    for (int j = threadIdx.x; j < nb; j += blockDim.x) {
        unsigned h = lh[j];
        if (h) atomicAdd(&histOut[j], h);
    }
}

// ---------------- sum of values strictly above threshold
__global__ void k_sum(const float* __restrict__ negv, int N, unsigned* __restrict__ scal) {
    unsigned tb = (scal[3] << 21) | (scal[5] << 10) | scal[7];
    float s = 0.f;
    for (int i = blockIdx.x * blockDim.x + threadIdx.x; i < N; i += gridDim.x * blockDim.x) {
        unsigned u = __float_as_uint(negv[i]);
        if (u > tb) s += __uint_as_float(u);
    }
    for (int off = 32; off > 0; off >>= 1) s += __shfl_down(s, off, 64);
    __shared__ float rs[4];
    int wv = threadIdx.x >> 6;
    if ((threadIdx.x & 63) == 0) rs[wv] = s;
    __syncthreads();
    if (threadIdx.x == 0) {
        float ss = rs[0] + rs[1] + rs[2] + rs[3];
        if (ss != 0.f) atomicAdd((float*)&scal[9], ss);
    }
}

// ---------------- finalize
__global__ void k_final(const unsigned* __restrict__ scal, float* __restrict__ out) {
    if (threadIdx.x == 0 && blockIdx.x == 0) {
        float k = (float)scal[0];
        float t = __uint_as_float((scal[3] << 21) | (scal[5] << 10) | scal[7]);
        float neg_sum = ((const float*)scal)[9] + (float)scal[8] * t;
        float smooth = ((const float*)scal)[2] / (k * 4.f);
        float ent = (((const float*)scal)[1] + neg_sum) / k;
        out[0] = smooth + ent;
    }
}

extern "C" void kernel_launch(void* const* d_in, const int* in_sizes, int n_in,
                              void* d_out, int out_size, void* d_ws, size_t ws_size,
                              hipStream_t stream) {
    const float* x      = (const float*)d_in[0];
    const float* y      = (const float*)d_in[1];
    const float* boxes  = (const float*)d_in[2];
    const int*   labels = (const int*)d_in[3];
    const float* dflt   = (const float*)d_in[4];
    float* out = (float*)d_out;

    int A = in_sizes[4] / 4;
    int B = in_sizes[1] / (2 * A);
    int M = in_sizes[3] / B;
    int N = B * A;

    unsigned* ws    = (unsigned*)d_ws;
    unsigned* match = ws;
    float*    negv  = (float*)(ws + (size_t)N);
    unsigned* hist1 = ws + (size_t)2 * N;
    unsigned* hist2 = hist1 + 2048;
    unsigned* hist3 = hist2 + 2048;
    unsigned* scal  = hist3 + 1024;
    int nzero = 2048 + 2048 + 1024 + 16;

    int chunks = (A + 255) / 256;
    k_match<<<dim3(B * chunks), dim3(256), 0, stream>>>(boxes, dflt, match, hist1, nzero, B, A, M, chunks);
    int waves = B * M;
    k_bestanchor<<<dim3((waves * 64 + 255) / 256), dim3(256), 0, stream>>>(boxes, dflt, match, B, A, M);
    k_main<<<dim3((N + 255) / 256), dim3(256), 0, stream>>>(x, y, boxes, labels, dflt, match,
                                                            negv, hist1, scal, B, A, M, N);
    k_scan<<<dim3(1), dim3(256), 0, stream>>>(hist1, 2048, scal, 0, 3, 4);
    k_refine<<<dim3(256), dim3(256), 0, stream>>>(negv, N, scal, hist2, 2);
    k_scan<<<dim3(1), dim3(256), 0, stream>>>(hist2, 2048, scal, 4, 5, 6);
    k_refine<<<dim3(256), dim3(256), 0, stream>>>(negv, N, scal, hist3, 3);
    k_scan<<<dim3(1), dim3(256), 0, stream>>>(hist3, 1024, scal, 6, 7, 8);
    k_sum<<<dim3(256), dim3(256), 0, stream>>>(negv, N, scal);
    k_final<<<dim3(1), dim3(64), 0, stream>>>(scal, out);
}

// Round 2
// 229.387 us; speedup vs baseline: 1.2450x; 1.2450x over previous
//
#include <hip/hip_runtime.h>

#define THRESH 0.5f

// ---------------- zero-init workspace scalars/hists/bestbox
__global__ void k_zero(unsigned* __restrict__ p, int n) {
    int i = blockIdx.x * blockDim.x + threadIdx.x;
    if (i < n) p[i] = 0u;
}

// ---------------- Kernel 1a: per-anchor match (argmax over boxes)
__global__ void k_match(const float* __restrict__ boxes, const float* __restrict__ dflt,
                        unsigned* __restrict__ match, int B, int A, int M, int chunks) {
    __shared__ float bx[512];
    __shared__ float barea[128];
    int b = blockIdx.x / chunks;
    int a = (blockIdx.x % chunks) * 256 + threadIdx.x;
    for (int j = threadIdx.x; j < M * 4; j += blockDim.x)
        bx[j] = boxes[(size_t)b * M * 4 + j];
    __syncthreads();
    if (threadIdx.x < M) {
        float x1 = bx[threadIdx.x*4], y1 = bx[threadIdx.x*4+1];
        float x2 = bx[threadIdx.x*4+2], y2 = bx[threadIdx.x*4+3];
        barea[threadIdx.x] = (x2 - x1) * (y2 - y1);
    }
    __syncthreads();
    if (a >= A) return;
    float4 dv = *reinterpret_cast<const float4*>(dflt + (size_t)a * 4);
    float dx1 = dv.x - dv.z*0.5f, dy1 = dv.y - dv.w*0.5f;
    float dx2 = dv.x + dv.z*0.5f, dy2 = dv.y + dv.w*0.5f;
    float darea = (dx2 - dx1) * (dy2 - dy1);
    float best = -1.0f; int bi = 0;
    for (int m = 0; m < M; ++m) {
        float x1 = bx[m*4], y1 = bx[m*4+1], x2 = bx[m*4+2], y2 = bx[m*4+3];
        float lx = fmaxf(x1, dx1), ly = fmaxf(y1, dy1);
        float rx = fminf(x2, dx2), ry = fminf(y2, dy2);
        float w = fmaxf(rx - lx, 0.f), h = fmaxf(ry - ly, 0.f);
        float inter = w * h;
        float iou = inter / (barea[m] + darea - inter);
        if (iou > best) { best = iou; bi = m; }
    }
    unsigned fl = (best >= THRESH) ? (1u << 30) : 0u;
    match[(size_t)b * A + a] = (unsigned)bi | fl;
}

// ---------------- Kernel 1b: per-box best anchor, block-parallel over anchor chunks.
// lane = box index, each wave scans 64 anchors via wave-uniform scalar loads.
// Exact argmax semantics: pack (iou_bits<<32 | ~anchor) so max => highest iou,
// ties => lowest anchor (JAX argmax first-index).
__global__ void k_bestanchor(const float* __restrict__ boxes, const float* __restrict__ dflt,
                             unsigned long long* __restrict__ bestbox,
                             int B, int A, int M, int chunks) {
    __shared__ unsigned long long lm[64];
    int b = blockIdx.x / chunks;
    int wv = threadIdx.x >> 6;
    int lane = threadIdx.x & 63;
    int abase = (blockIdx.x % chunks) * 256 + wv * 64;
    if (threadIdx.x < 64) lm[threadIdx.x] = 0ull;
    __syncthreads();
    int m = lane;
    bool mact = (m < M);
    float x1 = 0.f, y1 = 0.f, x2 = 0.f, y2 = 0.f, ba = 0.f;
    if (mact) {
        float4 bv = *reinterpret_cast<const float4*>(boxes + ((size_t)b * M + m) * 4);
        x1 = bv.x; y1 = bv.y; x2 = bv.z; y2 = bv.w;
        ba = (x2 - x1) * (y2 - y1);
    }
    float best = -1.0f; int abest = 0;
    #pragma unroll 8
    for (int k = 0; k < 64; ++k) {
        int aidx = __builtin_amdgcn_readfirstlane(abase + k);
        if (aidx >= A) break;  // wave-uniform
        float4 dv = *reinterpret_cast<const float4*>(dflt + (size_t)aidx * 4);
        float dx1 = dv.x - dv.z*0.5f, dy1 = dv.y - dv.w*0.5f;
        float dx2 = dv.x + dv.z*0.5f, dy2 = dv.y + dv.w*0.5f;
        float darea = (dx2 - dx1) * (dy2 - dy1);
        float lx = fmaxf(x1, dx1), ly = fmaxf(y1, dy1);
        float rx = fminf(x2, dx2), ry = fminf(y2, dy2);
        float w = fmaxf(rx - lx, 0.f), h = fmaxf(ry - ly, 0.f);
        float inter = w * h;
        float iou = inter / (ba + darea - inter);
        if (iou > best) { best = iou; abest = aidx; }  // ascending aidx => first-max kept
    }
    if (mact && best >= 0.f)
        atomicMax(&lm[m], ((unsigned long long)__float_as_uint(best) << 32) |
                          (unsigned long long)(unsigned)(~abest));
    __syncthreads();
    if (threadIdx.x < M) {
        unsigned long long p = lm[threadIdx.x];
        if (p) atomicMax(&bestbox[(size_t)b * M + threadIdx.x], p);
    }
}

// ---------------- Kernel 1c: apply force-match override (last box wins via max m)
__global__ void k_override(const unsigned long long* __restrict__ bestbox,
                           unsigned* __restrict__ match, int B, int A, int M) {
    int i = blockIdx.x * blockDim.x + threadIdx.x;
    if (i >= B * M) return;
    unsigned long long p = bestbox[i];
    unsigned a = ~(unsigned)(p & 0xFFFFFFFFull);
    if (a < (unsigned)A) {
        int b = i / M, m = i % M;
        atomicMax(&match[(size_t)b * A + a], 0x80000000u | (unsigned)m);
    }
}

// ---------------- Kernel 2: main fused pass
__global__ void k_main(const float* __restrict__ x, const float* __restrict__ y,
                       const float* __restrict__ boxes, const int* __restrict__ labels,
                       const float* __restrict__ dflt, const unsigned* __restrict__ match,
                       float* __restrict__ negv, unsigned* __restrict__ hist1,
                       unsigned* __restrict__ scal, int B, int A, int M, int N) {
    __shared__ unsigned lh[2048];
    for (int j = threadIdx.x; j < 2048; j += blockDim.x) lh[j] = 0u;
    __syncthreads();
    int i = blockIdx.x * blockDim.x + threadIdx.x;
    float l_smooth = 0.f, l_pos = 0.f; int l_cnt = 0;
    if (i < N) {
        int b = i / A, a = i % A;
        unsigned w = match[i];
        int digit = (int)(w & 0xFFFFu);
        int flag = (w & 0x80000000u) ? 1 : (int)((w >> 30) & 1u);
        int lab = labels[b * M + digit];
        int c = flag ? lab : 0;
        bool pos = (c == 1);
        const float* bp = boxes + ((size_t)b * M + digit) * 4;
        float bx1 = bp[0], by1 = bp[1], bx2 = bp[2], by2 = bp[3];
        float cw = bx2 - bx1, ch = by2 - by1;
        float ccx = (bx1 + bx2) * 0.5f, ccy = (by1 + by2) * 0.5f;
        const float* dp = dflt + (size_t)a * 4;
        float dcx = dp[0], dcy = dp[1], dw = dp[2], dh = dp[3];
        float loc[4];
        loc[0] = (ccx - dcx) / (dw * 0.1f);
        loc[1] = (ccy - dcy) / (dh * 0.1f);
        loc[2] = logf(cw / dw) * 5.f;
        loc[3] = logf(ch / dh) * 5.f;
        const float* xp = x + (size_t)i * 4;
        float s = 0.f;
        for (int j = 0; j < 4; ++j) {
            float d = xp[j] - loc[j];
            float ad = fabsf(d);
            s += (ad < 1.f) ? 0.5f * d * d : (ad - 0.5f);
        }
        float y0 = y[(size_t)i * 2], y1v = y[(size_t)i * 2 + 1];
        float mx = fmaxf(y0, y1v);
        float lse = mx + logf(expf(y0 - mx) + expf(y1v - mx));
        float yc = (c == 0) ? y0 : y1v;
        float ent = lse - yc;
        float v = pos ? 0.f : ent;
        negv[i] = v;
        if (pos) { l_smooth = s; l_pos = ent; l_cnt = 1; }
        atomicAdd(&lh[__float_as_uint(v) >> 21], 1u);
    }
    for (int off = 32; off > 0; off >>= 1) {
        l_smooth += __shfl_down(l_smooth, off, 64);
        l_pos    += __shfl_down(l_pos, off, 64);
        l_cnt    += __shfl_down(l_cnt, off, 64);
    }
    __shared__ float rs[4], rp[4]; __shared__ int rc[4];
    int wv = threadIdx.x >> 6;
    if ((threadIdx.x & 63) == 0) { rs[wv] = l_smooth; rp[wv] = l_pos; rc[wv] = l_cnt; }
    __syncthreads();
    if (threadIdx.x == 0) {
        float ss = rs[0] + rs[1] + rs[2] + rs[3];
        float pp = rp[0] + rp[1] + rp[2] + rp[3];
        int   cc = rc[0] + rc[1] + rc[2] + rc[3];
        if (ss != 0.f) atomicAdd((float*)&scal[2], ss);
        if (pp != 0.f) atomicAdd((float*)&scal[1], pp);
        if (cc)        atomicAdd((int*)&scal[0], cc);
    }
    __syncthreads();
    for (int j = threadIdx.x; j < 2048; j += blockDim.x) {
        unsigned h = lh[j];
        if (h) atomicAdd(&hist1[j], h);
    }
}

// ---------------- scan a histogram, find bin containing k-th largest
__global__ void k_scan(const unsigned* __restrict__ hist, int nbins,
                       unsigned* __restrict__ scal, int kIdx, int bIdx, int kOutIdx) {
    __shared__ unsigned ts[256];
    int t = threadIdx.x;
    int per = nbins / 256;
    unsigned k = scal[kIdx];
    unsigned s = 0;
    for (int j = 0; j < per; ++j) s += hist[t * per + j];
    ts[t] = s;
    __syncthreads();
    for (int off = 1; off < 256; off <<= 1) {
        unsigned add = (t >= off) ? ts[t - off] : 0u;
        __syncthreads();
        ts[t] += add;
        __syncthreads();
    }
    unsigned total = ts[255];
    unsigned P = (t == 0) ? 0u : ts[t - 1];
    for (int j = 0; j < per; ++j) {
        unsigned h = hist[t * per + j];
        P += h;
        unsigned above = total - P;
        if (above < k && k <= above + h) {
            scal[bIdx] = (unsigned)(t * per + j);
            scal[kOutIdx] = k - above;
        }
    }
}

// ---------------- refine histogram at level 2 or 3
__global__ void k_refine(const float* __restrict__ negv, int N,
                         const unsigned* __restrict__ scal,
                         unsigned* __restrict__ histOut, int level) {
    __shared__ unsigned lh[2048];
    int nb = (level == 2) ? 2048 : 1024;
    for (int j = threadIdx.x; j < nb; j += blockDim.x) lh[j] = 0u;
    __syncthreads();
    unsigned prefix = (level == 2) ? scal[3] : ((scal[3] << 11) | scal[5]);
    int shiftm = (level == 2) ? 21 : 10;
    for (int i = blockIdx.x * blockDim.x + threadIdx.x; i < N; i += gridDim.x * blockDim.x) {
        unsigned u = __float_as_uint(negv[i]);
        if ((u >> shiftm) == prefix) {
            unsigned bin = (level == 2) ? ((u >> 10) & 0x7FFu) : (u & 0x3FFu);
            atomicAdd(&lh[bin], 1u);
        }
    }
    __syncthreads();
    for (int j = threadIdx.x; j < nb; j += blockDim.x) {
        unsigned h = lh[j];
        if (h) atomicAdd(&histOut[j], h);
    }
}

// ---------------- sum of values strictly above threshold
__global__ void k_sum(const float* __restrict__ negv, int N, unsigned* __restrict__ scal) {
    unsigned tb = (scal[3] << 21) | (scal[5] << 10) | scal[7];
    float s = 0.f;
    for (int i = blockIdx.x * blockDim.x + threadIdx.x; i < N; i += gridDim.x * blockDim.x) {
        unsigned u = __float_as_uint(negv[i]);
        if (u > tb) s += __uint_as_float(u);
    }
    for (int off = 32; off > 0; off >>= 1) s += __shfl_down(s, off, 64);
    __shared__ float rs[4];
    int wv = threadIdx.x >> 6;
    if ((threadIdx.x & 63) == 0) rs[wv] = s;
    __syncthreads();
    if (threadIdx.x == 0) {
        float ss = rs[0] + rs[1] + rs[2] + rs[3];
        if (ss != 0.f) atomicAdd((float*)&scal[9], ss);
    }
}

// ---------------- finalize
__global__ void k_final(const unsigned* __restrict__ scal, float* __restrict__ out) {
    if (threadIdx.x == 0 && blockIdx.x == 0) {
        float k = (float)scal[0];
        float t = __uint_as_float((scal[3] << 21) | (scal[5] << 10) | scal[7]);
        float neg_sum = ((const float*)scal)[9] + (float)scal[8] * t;
        float smooth = ((const float*)scal)[2] / (k * 4.f);
        float ent = (((const float*)scal)[1] + neg_sum) / k;
        out[0] = smooth + ent;
    }
}

extern "C" void kernel_launch(void* const* d_in, const int* in_sizes, int n_in,
                              void* d_out, int out_size, void* d_ws, size_t ws_size,
                              hipStream_t stream) {
    const float* x      = (const float*)d_in[0];
    const float* y      = (const float*)d_in[1];
    const float* boxes  = (const float*)d_in[2];
    const int*   labels = (const int*)d_in[3];
    const float* dflt   = (const float*)d_in[4];
    float* out = (float*)d_out;

    int A = in_sizes[4] / 4;
    int B = in_sizes[1] / (2 * A);
    int M = in_sizes[3] / B;
    int N = B * A;

    unsigned* ws    = (unsigned*)d_ws;
    unsigned* match = ws;                                   // N u32
    float*    negv  = (float*)(ws + (size_t)N);             // N f32
    unsigned long long* bestbox = (unsigned long long*)(ws + (size_t)2 * N);  // B*M u64
    unsigned* hist1 = ws + (size_t)2 * N + 2 * B * M;       // 2048
    unsigned* hist2 = hist1 + 2048;                         // 2048
    unsigned* hist3 = hist2 + 2048;                         // 1024
    unsigned* scal  = hist3 + 1024;                         // 16
    int nzero = 2 * B * M + 2048 + 2048 + 1024 + 16;

    int chunks = (A + 255) / 256;
    k_zero<<<dim3((nzero + 255) / 256), dim3(256), 0, stream>>>(ws + (size_t)2 * N, nzero);
    k_match<<<dim3(B * chunks), dim3(256), 0, stream>>>(boxes, dflt, match, B, A, M, chunks);
    k_bestanchor<<<dim3(B * chunks), dim3(256), 0, stream>>>(boxes, dflt, bestbox, B, A, M, chunks);
    k_override<<<dim3((B * M + 255) / 256), dim3(256), 0, stream>>>(bestbox, match, B, A, M);
    k_main<<<dim3((N + 255) / 256), dim3(256), 0, stream>>>(x, y, boxes, labels, dflt, match,
                                                            negv, hist1, scal, B, A, M, N);
    k_scan<<<dim3(1), dim3(256), 0, stream>>>(hist1, 2048, scal, 0, 3, 4);
    k_refine<<<dim3(256), dim3(256), 0, stream>>>(negv, N, scal, hist2, 2);
    k_scan<<<dim3(1), dim3(256), 0, stream>>>(hist2, 2048, scal, 4, 5, 6);
    k_refine<<<dim3(256), dim3(256), 0, stream>>>(negv, N, scal, hist3, 3);
    k_scan<<<dim3(1), dim3(256), 0, stream>>>(hist3, 1024, scal, 6, 7, 8);
    k_sum<<<dim3(256), dim3(256), 0, stream>>>(negv, N, scal);
    k_final<<<dim3(1), dim3(64), 0, stream>>>(scal, out);
}

// Round 3
// 170.075 us; speedup vs baseline: 1.6792x; 1.3487x over previous
//
#include <hip/hip_runtime.h>

#define THRESH 0.5f

// ---------------- zero-init bestbox/hists/scalars
__global__ void k_zero(unsigned* __restrict__ p, int n) {
    int i = blockIdx.x * blockDim.x + threadIdx.x;
    if (i < n) p[i] = 0u;
}

// ---------------- fused: per-anchor match (argmax over boxes) + per-box best anchor
__global__ void __launch_bounds__(256) k_matchboth(
        const float* __restrict__ boxes, const float* __restrict__ dflt,
        unsigned* __restrict__ match, unsigned long long* __restrict__ bestbox,
        int B, int A, int M, int chunks) {
    __shared__ float4 bx[128];
    __shared__ float barea[128];
    __shared__ float4 anch[256];
    __shared__ unsigned long long lm[128];
    int tid = threadIdx.x;
    int b = blockIdx.x / chunks;
    int chunk = blockIdx.x % chunks;
    int a = chunk * 256 + tid;
    if (tid < M) {
        float4 bv = *reinterpret_cast<const float4*>(boxes + ((size_t)b * M + tid) * 4);
        bx[tid] = bv;
        barea[tid] = (bv.z - bv.x) * (bv.w - bv.y);
        lm[tid] = 0ull;
    }
    bool aval = (a < A);
    float dx1 = 0.f, dy1 = 0.f, dx2 = 0.f, dy2 = 0.f;
    if (aval) {
        float4 dv = *reinterpret_cast<const float4*>(dflt + (size_t)a * 4);
        dx1 = dv.x - dv.z * 0.5f; dy1 = dv.y - dv.w * 0.5f;
        dx2 = dv.x + dv.z * 0.5f; dy2 = dv.y + dv.w * 0.5f;
    }
    anch[tid] = make_float4(dx1, dy1, dx2, dy2);
    __syncthreads();
    // phase 1: thread = anchor, loop over boxes (LDS broadcast)
    if (aval) {
        float darea = (dx2 - dx1) * (dy2 - dy1);
        float best = -1.0f; int bi = 0;
        for (int m = 0; m < M; ++m) {
            float4 bb = bx[m];
            float lx = fmaxf(bb.x, dx1), ly = fmaxf(bb.y, dy1);
            float rx = fminf(bb.z, dx2), ry = fminf(bb.w, dy2);
            float w = fmaxf(rx - lx, 0.f), h = fmaxf(ry - ly, 0.f);
            float inter = w * h;
            float iou = inter / (barea[m] + darea - inter);
            if (iou > best) { best = iou; bi = m; }
        }
        match[(size_t)b * A + a] = (unsigned)bi | ((best >= THRESH) ? (1u << 30) : 0u);
    }
    // phase 2: lane = box, wave scans its 64 anchors (LDS broadcast reads)
    int wv = tid >> 6, lane = tid & 63;
    int abase = chunk * 256 + wv * 64;
    if (lane < M) {
        float4 bb = bx[lane];
        float ba = barea[lane];
        float best = -1.0f; int abest = 0;
        for (int k = 0; k < 64; ++k) {
            int aidx = abase + k;
            if (aidx >= A) break;  // wave-uniform
            float4 av = anch[wv * 64 + k];
            float darea = (av.z - av.x) * (av.w - av.y);
            float lx = fmaxf(bb.x, av.x), ly = fmaxf(bb.y, av.y);
            float rx = fminf(bb.z, av.z), ry = fminf(bb.w, av.w);
            float w = fmaxf(rx - lx, 0.f), h = fmaxf(ry - ly, 0.f);
            float inter = w * h;
            float iou = inter / (ba + darea - inter);
            if (iou > best) { best = iou; abest = aidx; }  // strict > : first max kept
        }
        if (best >= 0.f)
            atomicMax(&lm[lane], ((unsigned long long)__float_as_uint(best) << 32) |
                                 (unsigned long long)(unsigned)(~abest));
    }
    __syncthreads();
    if (tid < M) {
        unsigned long long p = lm[tid];
        if (p) atomicMax(&bestbox[(size_t)b * M + tid], p);
    }
}

// ---------------- apply force-match override (last box wins via max m)
__global__ void k_override(const unsigned long long* __restrict__ bestbox,
                           unsigned* __restrict__ match, int B, int A, int M) {
    int i = blockIdx.x * blockDim.x + threadIdx.x;
    if (i >= B * M) return;
    unsigned long long p = bestbox[i];
    unsigned a = ~(unsigned)(p & 0xFFFFFFFFull);
    if (a < (unsigned)A) {
        int b = i / M, m = i % M;
        atomicMax(&match[(size_t)b * A + a], 0x80000000u | (unsigned)m);
    }
}

// ---------------- main fused pass, 4 elements/thread, one batch per block
__global__ void __launch_bounds__(256) k_main(
        const float* __restrict__ x, const float* __restrict__ y,
        const float* __restrict__ boxes, const int* __restrict__ labels,
        const float* __restrict__ dflt, const unsigned* __restrict__ match,
        float* __restrict__ negv, unsigned* __restrict__ hist1,
        unsigned* __restrict__ scal, int A, int M, int N) {
    __shared__ unsigned lh[2048];
    __shared__ float4 sbx[128];
    __shared__ int slab[128];
    for (int j = threadIdx.x; j < 2048; j += 256) lh[j] = 0u;
    int i0 = (blockIdx.x * 256 + threadIdx.x) * 4;
    int b = (int)(((size_t)blockIdx.x * 1024) / (size_t)A);  // block spans one batch (A % 1024 == 0)
    if (threadIdx.x < M) {
        sbx[threadIdx.x] = *reinterpret_cast<const float4*>(boxes + ((size_t)b * M + threadIdx.x) * 4);
        slab[threadIdx.x] = labels[b * M + threadIdx.x];
    }
    __syncthreads();
    float l_smooth = 0.f, l_pos = 0.f; int l_cnt = 0;
    if (i0 + 3 < N) {
        int a0 = i0 - b * A;
        uint4 w4 = *reinterpret_cast<const uint4*>(match + i0);
        const float4* xp = reinterpret_cast<const float4*>(x + (size_t)i0 * 4);
        float4 xs[4] = {xp[0], xp[1], xp[2], xp[3]};
        const float4* yp = reinterpret_cast<const float4*>(y + (size_t)i0 * 2);
        float4 ya = yp[0], yb = yp[1];
        const float4* dp = reinterpret_cast<const float4*>(dflt + (size_t)a0 * 4);
        unsigned wws[4] = {w4.x, w4.y, w4.z, w4.w};
        float y0s[4] = {ya.x, ya.z, yb.x, yb.z};
        float y1s[4] = {ya.y, ya.w, yb.y, yb.w};
        float vs[4];
        #pragma unroll
        for (int e = 0; e < 4; ++e) {
            unsigned w = wws[e];
            int digit = (int)(w & 0xFFFFu);
            bool flag = (w & 0xC0000000u) != 0u;   // override(bit31) or overlap>=thr(bit30)
            int c = flag ? slab[digit] : 0;
            bool pos = (c == 1);
            float4 bv = sbx[digit];
            float4 dv = dp[e];
            float cw = bv.z - bv.x, ch = bv.w - bv.y;
            float ccx = (bv.x + bv.z) * 0.5f, ccy = (bv.y + bv.w) * 0.5f;
            float l0 = (ccx - dv.x) / (dv.z * 0.1f);
            float l1 = (ccy - dv.y) / (dv.w * 0.1f);
            float l2 = logf(cw / dv.z) * 5.f;
            float l3 = logf(ch / dv.w) * 5.f;
            float4 xv = xs[e];
            float s = 0.f, d, ad;
            d = xv.x - l0; ad = fabsf(d); s += (ad < 1.f) ? 0.5f * d * d : ad - 0.5f;
            d = xv.y - l1; ad = fabsf(d); s += (ad < 1.f) ? 0.5f * d * d : ad - 0.5f;
            d = xv.z - l2; ad = fabsf(d); s += (ad < 1.f) ? 0.5f * d * d : ad - 0.5f;
            d = xv.w - l3; ad = fabsf(d); s += (ad < 1.f) ? 0.5f * d * d : ad - 0.5f;
            float y0 = y0s[e], y1v = y1s[e];
            float mx = fmaxf(y0, y1v);
            float lse = mx + logf(expf(y0 - mx) + expf(y1v - mx));
            float ent = lse - ((c == 0) ? y0 : y1v);
            float v = pos ? 0.f : ent;
            vs[e] = v;
            if (pos) { l_smooth += s; l_pos += ent; l_cnt += 1; }
            atomicAdd(&lh[__float_as_uint(v) >> 21], 1u);
        }
        *reinterpret_cast<float4*>(negv + i0) = make_float4(vs[0], vs[1], vs[2], vs[3]);
    }
    for (int off = 32; off > 0; off >>= 1) {
        l_smooth += __shfl_down(l_smooth, off, 64);
        l_pos    += __shfl_down(l_pos, off, 64);
        l_cnt    += __shfl_down(l_cnt, off, 64);
    }
    __shared__ float rs[4], rp[4]; __shared__ int rc[4];
    int wv = threadIdx.x >> 6;
    if ((threadIdx.x & 63) == 0) { rs[wv] = l_smooth; rp[wv] = l_pos; rc[wv] = l_cnt; }
    __syncthreads();
    if (threadIdx.x == 0) {
        float ss = rs[0] + rs[1] + rs[2] + rs[3];
        float pp = rp[0] + rp[1] + rp[2] + rp[3];
        int   cc = rc[0] + rc[1] + rc[2] + rc[3];
        if (ss != 0.f) atomicAdd((float*)&scal[2], ss);
        if (pp != 0.f) atomicAdd((float*)&scal[1], pp);
        if (cc)        atomicAdd((int*)&scal[0], cc);
    }
    __syncthreads();
    for (int j = threadIdx.x; j < 2048; j += 256) {
        unsigned h = lh[j];
        if (h) atomicAdd(&hist1[j], h);
    }
}

// ---------------- block-cooperative: find bin containing k-th largest in hist
__device__ __forceinline__ void scan_find(const unsigned* __restrict__ hist, int nbins,
                                          unsigned k, unsigned* ts, unsigned* res) {
    int t = threadIdx.x;
    int per = nbins >> 8;
    unsigned s = 0;
    for (int j = 0; j < per; ++j) s += hist[t * per + j];
    ts[t] = s;
    __syncthreads();
    for (int off = 1; off < 256; off <<= 1) {
        unsigned add = (t >= off) ? ts[t - off] : 0u;
        __syncthreads();
        ts[t] += add;
        __syncthreads();
    }
    unsigned total = ts[255];
    unsigned P = (t == 0) ? 0u : ts[t - 1];
    for (int j = 0; j < per; ++j) {
        unsigned h = hist[t * per + j];
        P += h;
        unsigned above = total - P;
        if (above < k && k <= above + h) { res[0] = (unsigned)(t * per + j); res[1] = k - above; }
    }
    __syncthreads();
}

// ---------------- level-2 refine (scans hist1 inline)
__global__ void __launch_bounds__(256) k_refine2(
        const float* __restrict__ negv, int N, const unsigned* __restrict__ scal,
        const unsigned* __restrict__ hist1, unsigned* __restrict__ hist2) {
    __shared__ unsigned ts[256], res[2], lh[2048];
    scan_find(hist1, 2048, scal[0], ts, res);
    unsigned bin1 = res[0];
    for (int j = threadIdx.x; j < 2048; j += 256) lh[j] = 0u;
    __syncthreads();
    for (int i = (blockIdx.x * 256 + threadIdx.x) * 4; i < N; i += gridDim.x * 1024) {
        float4 v4 = *reinterpret_cast<const float4*>(negv + i);
        unsigned u;
        u = __float_as_uint(v4.x); if ((u >> 21) == bin1) atomicAdd(&lh[(u >> 10) & 0x7FFu], 1u);
        u = __float_as_uint(v4.y); if ((u >> 21) == bin1) atomicAdd(&lh[(u >> 10) & 0x7FFu], 1u);
        u = __float_as_uint(v4.z); if ((u >> 21) == bin1) atomicAdd(&lh[(u >> 10) & 0x7FFu], 1u);
        u = __float_as_uint(v4.w); if ((u >> 21) == bin1) atomicAdd(&lh[(u >> 10) & 0x7FFu], 1u);
    }
    __syncthreads();
    for (int j = threadIdx.x; j < 2048; j += 256) {
        unsigned h = lh[j];
        if (h) atomicAdd(&hist2[j], h);
    }
}

// ---------------- level-3 refine (scans hist1+hist2 inline)
__global__ void __launch_bounds__(256) k_refine3(
        const float* __restrict__ negv, int N, const unsigned* __restrict__ scal,
        const unsigned* __restrict__ hist1, const unsigned* __restrict__ hist2,
        unsigned* __restrict__ hist3) {
    __shared__ unsigned ts[256], res[2], lh[1024];
    scan_find(hist1, 2048, scal[0], ts, res);
    unsigned bin1 = res[0], k1 = res[1];
    scan_find(hist2, 2048, k1, ts, res);
    unsigned prefix = (bin1 << 11) | res[0];
    for (int j = threadIdx.x; j < 1024; j += 256) lh[j] = 0u;
    __syncthreads();
    for (int i = (blockIdx.x * 256 + threadIdx.x) * 4; i < N; i += gridDim.x * 1024) {
        float4 v4 = *reinterpret_cast<const float4*>(negv + i);
        unsigned u;
        u = __float_as_uint(v4.x); if ((u >> 10) == prefix) atomicAdd(&lh[u & 0x3FFu], 1u);
        u = __float_as_uint(v4.y); if ((u >> 10) == prefix) atomicAdd(&lh[u & 0x3FFu], 1u);
        u = __float_as_uint(v4.z); if ((u >> 10) == prefix) atomicAdd(&lh[u & 0x3FFu], 1u);
        u = __float_as_uint(v4.w); if ((u >> 10) == prefix) atomicAdd(&lh[u & 0x3FFu], 1u);
    }
    __syncthreads();
    for (int j = threadIdx.x; j < 1024; j += 256) {
        unsigned h = lh[j];
        if (h) atomicAdd(&hist3[j], h);
    }
}

// ---------------- sum of values strictly above threshold (scans all hists inline)
__global__ void __launch_bounds__(256) k_sum(
        const float* __restrict__ negv, int N, unsigned* __restrict__ scal,
        const unsigned* __restrict__ hist1, const unsigned* __restrict__ hist2,
        const unsigned* __restrict__ hist3) {
    __shared__ unsigned ts[256], res[2];
    scan_find(hist1, 2048, scal[0], ts, res);
    unsigned bin1 = res[0], k1 = res[1];
    scan_find(hist2, 2048, k1, ts, res);
    unsigned bin2 = res[0], k2 = res[1];
    scan_find(hist3, 1024, k2, ts, res);
    unsigned bin3 = res[0], k3 = res[1];
    unsigned tb = (bin1 << 21) | (bin2 << 10) | bin3;
    float s = 0.f;
    for (int i = (blockIdx.x * 256 + threadIdx.x) * 4; i < N; i += gridDim.x * 1024) {
        float4 v4 = *reinterpret_cast<const float4*>(negv + i);
        unsigned u;
        u = __float_as_uint(v4.x); if (u > tb) s += v4.x;
        u = __float_as_uint(v4.y); if (u > tb) s += v4.y;
        u = __float_as_uint(v4.z); if (u > tb) s += v4.z;
        u = __float_as_uint(v4.w); if (u > tb) s += v4.w;
    }
    for (int off = 32; off > 0; off >>= 1) s += __shfl_down(s, off, 64);
    __shared__ float rsum[4];
    int wv = threadIdx.x >> 6;
    if ((threadIdx.x & 63) == 0) rsum[wv] = s;
    __syncthreads();
    if (threadIdx.x == 0) {
        float ss = rsum[0] + rsum[1] + rsum[2] + rsum[3];
        if (ss != 0.f) atomicAdd((float*)&scal[9], ss);
        if (blockIdx.x == 0) { scal[10] = tb; scal[8] = k3; }
    }
}

// ---------------- finalize
__global__ void k_final(const unsigned* __restrict__ scal, float* __restrict__ out) {
    if (threadIdx.x == 0 && blockIdx.x == 0) {
        const float* f = (const float*)scal;
        float k = (float)scal[0];
        float t = __uint_as_float(scal[10]);
        float neg_sum = f[9] + (float)scal[8] * t;
        float smooth = f[2] / (k * 4.f);
        float ent = (f[1] + neg_sum) / k;
        out[0] = smooth + ent;
    }
}

extern "C" void kernel_launch(void* const* d_in, const int* in_sizes, int n_in,
                              void* d_out, int out_size, void* d_ws, size_t ws_size,
                              hipStream_t stream) {
    const float* x      = (const float*)d_in[0];
    const float* y      = (const float*)d_in[1];
    const float* boxes  = (const float*)d_in[2];
    const int*   labels = (const int*)d_in[3];
    const float* dflt   = (const float*)d_in[4];
    float* out = (float*)d_out;

    int A = in_sizes[4] / 4;
    int B = in_sizes[1] / (2 * A);
    int M = in_sizes[3] / B;
    int N = B * A;

    unsigned* ws    = (unsigned*)d_ws;
    unsigned* match = ws;                                       // N u32
    float*    negv  = (float*)(ws + (size_t)N);                 // N f32
    unsigned long long* bestbox = (unsigned long long*)(ws + (size_t)2 * N);  // B*M u64
    unsigned* hist1 = ws + (size_t)2 * N + 2 * B * M;           // 2048
    unsigned* hist2 = hist1 + 2048;                             // 2048
    unsigned* hist3 = hist2 + 2048;                             // 1024
    unsigned* scal  = hist3 + 1024;                             // 16
    int nzero = 2 * B * M + 2048 + 2048 + 1024 + 16;

    int chunks = (A + 255) / 256;
    k_zero<<<dim3((nzero + 255) / 256), dim3(256), 0, stream>>>(ws + (size_t)2 * N, nzero);
    k_matchboth<<<dim3(B * chunks), dim3(256), 0, stream>>>(boxes, dflt, match, bestbox, B, A, M, chunks);
    k_override<<<dim3((B * M + 255) / 256), dim3(256), 0, stream>>>(bestbox, match, B, A, M);
    k_main<<<dim3(N / 1024), dim3(256), 0, stream>>>(x, y, boxes, labels, dflt, match,
                                                     negv, hist1, scal, A, M, N);
    k_refine2<<<dim3(512), dim3(256), 0, stream>>>(negv, N, scal, hist1, hist2);
    k_refine3<<<dim3(512), dim3(256), 0, stream>>>(negv, N, scal, hist1, hist2, hist3);
    k_sum<<<dim3(512), dim3(256), 0, stream>>>(negv, N, scal, hist1, hist2, hist3);
    k_final<<<dim3(1), dim3(64), 0, stream>>>(scal, out);
}

// Round 4
// 141.505 us; speedup vs baseline: 2.0182x; 1.2019x over previous
//
#include <hip/hip_runtime.h>

#define THRESH 0.5f

// ---------------- zero-init bestbox/hists/scalars
__global__ void k_zero(unsigned* __restrict__ p, int n) {
    int i = blockIdx.x * blockDim.x + threadIdx.x;
    if (i < n) p[i] = 0u;
}

// ---------------- fused: per-anchor match (argmax over boxes) + per-box best anchor
// Division-free: iou_k > iou_b  <=>  inter_k*S_b > inter_b*S_k  (S = area_a + area_b),
// since the inter_k*inter_b cross terms cancel exactly. iou >= 0.5 <=> 3*inter >= S.
__global__ void __launch_bounds__(256) k_matchboth(
        const float* __restrict__ boxes, const float* __restrict__ dflt,
        unsigned* __restrict__ match, unsigned long long* __restrict__ bestbox,
        int B, int A, int M, int chunks) {
    __shared__ float4 bx[128];
    __shared__ float barea[128];
    __shared__ float4 anch[256];
    __shared__ float adarea[256];
    __shared__ unsigned long long lm[128];
    int tid = threadIdx.x;
    int b = blockIdx.x / chunks;
    int chunk = blockIdx.x - b * chunks;
    int a = chunk * 256 + tid;
    if (tid < M) {
        float4 bv = *reinterpret_cast<const float4*>(boxes + ((size_t)b * M + tid) * 4);
        bx[tid] = bv;
        barea[tid] = (bv.z - bv.x) * (bv.w - bv.y);
        lm[tid] = 0ull;
    }
    bool aval = (a < A);
    float dx1 = 0.f, dy1 = 0.f, dx2 = 0.f, dy2 = 0.f, darea = 0.f;
    if (aval) {
        float4 dv = *reinterpret_cast<const float4*>(dflt + (size_t)a * 4);
        dx1 = dv.x - dv.z * 0.5f; dy1 = dv.y - dv.w * 0.5f;
        dx2 = dv.x + dv.z * 0.5f; dy2 = dv.y + dv.w * 0.5f;
        darea = (dx2 - dx1) * (dy2 - dy1);
    }
    anch[tid] = make_float4(dx1, dy1, dx2, dy2);
    adarea[tid] = darea;
    __syncthreads();
    // phase 1: thread = anchor, loop over boxes (LDS broadcast)
    if (aval) {
        float binter = -1.0f, bS = 1.0f; int bm = 0;
        #pragma unroll 4
        for (int m = 0; m < M; ++m) {
            float4 bb = bx[m];
            float lx = fmaxf(bb.x, dx1), ly = fmaxf(bb.y, dy1);
            float rx = fminf(bb.z, dx2), ry = fminf(bb.w, dy2);
            float w = fmaxf(rx - lx, 0.f), h = fmaxf(ry - ly, 0.f);
            float inter = w * h;
            float S = barea[m] + darea;
            bool gt = inter * bS > binter * S;   // strict >: first max kept
            binter = gt ? inter : binter;
            bS     = gt ? S : bS;
            bm     = gt ? m : bm;
        }
        unsigned fl = (3.0f * binter >= bS) ? (1u << 30) : 0u;  // iou >= 0.5
        match[(size_t)b * A + a] = (unsigned)bm | fl;
    }
    // phase 2: lane = box, wave scans its 64 anchors (LDS broadcast reads)
    int wv = tid >> 6, lane = tid & 63;
    int abase = chunk * 256 + wv * 64;
    int kmax = min(64, A - abase);
    if (lane < M && kmax > 0) {
        float4 bb = bx[lane];
        float ba = barea[lane];
        float binter = -1.0f, bS = 1.0f; int bk = 0;
        #pragma unroll 4
        for (int k = 0; k < kmax; ++k) {
            float4 av = anch[wv * 64 + k];
            float lx = fmaxf(bb.x, av.x), ly = fmaxf(bb.y, av.y);
            float rx = fminf(bb.z, av.z), ry = fminf(bb.w, av.w);
            float w = fmaxf(rx - lx, 0.f), h = fmaxf(ry - ly, 0.f);
            float inter = w * h;
            float S = ba + adarea[wv * 64 + k];
            bool gt = inter * bS > binter * S;
            binter = gt ? inter : binter;
            bS     = gt ? S : bS;
            bk     = gt ? k : bk;
        }
        float best = binter / (bS - binter);     // one div per lane (ordering key)
        atomicMax(&lm[lane], ((unsigned long long)__float_as_uint(best) << 32) |
                             (unsigned long long)(unsigned)(~(abase + bk)));
    }
    __syncthreads();
    if (tid < M) {
        unsigned long long p = lm[tid];
        if (p) atomicMax(&bestbox[(size_t)b * M + tid], p);
    }
}

// ---------------- apply force-match override (last box wins via max m)
__global__ void k_override(const unsigned long long* __restrict__ bestbox,
                           unsigned* __restrict__ match, int B, int A, int M) {
    int i = blockIdx.x * blockDim.x + threadIdx.x;
    if (i >= B * M) return;
    unsigned long long p = bestbox[i];
    unsigned a = ~(unsigned)(p & 0xFFFFFFFFull);
    if (a < (unsigned)A) {
        int b = i / M, m = i % M;
        atomicMax(&match[(size_t)b * A + a], 0x80000000u | (unsigned)m);
    }
}

// ---------------- main fused pass, 8 elements/thread, one batch per block
__global__ void __launch_bounds__(256) k_main(
        const float* __restrict__ x, const float* __restrict__ y,
        const float* __restrict__ boxes, const int* __restrict__ labels,
        const float* __restrict__ dflt, const unsigned* __restrict__ match,
        float* __restrict__ negv, unsigned* __restrict__ hist1,
        unsigned* __restrict__ scal, int A, int M, int N) {
    __shared__ unsigned lh[2048];
    __shared__ float4 sbx[128];
    __shared__ int slab[128];
    for (int j = threadIdx.x; j < 2048; j += 256) lh[j] = 0u;
    int i0 = (blockIdx.x * 256 + threadIdx.x) * 8;
    int b = (int)(((long long)blockIdx.x * 2048) / A);  // block spans one batch (A % 2048 == 0)
    if (threadIdx.x < M) {
        sbx[threadIdx.x] = *reinterpret_cast<const float4*>(boxes + ((size_t)b * M + threadIdx.x) * 4);
        slab[threadIdx.x] = labels[b * M + threadIdx.x];
    }
    __syncthreads();
    float l_smooth = 0.f, l_pos = 0.f; int l_cnt = 0;
    if (i0 + 7 < N) {
        int a0 = i0 - b * A;
        const uint4* mp = reinterpret_cast<const uint4*>(match + i0);
        uint4 w4a = mp[0], w4b = mp[1];
        const float4* xp = reinterpret_cast<const float4*>(x + (size_t)i0 * 4);
        float4 xs[8];
        #pragma unroll
        for (int e = 0; e < 8; ++e) xs[e] = xp[e];
        const float4* yp = reinterpret_cast<const float4*>(y + (size_t)i0 * 2);
        float4 yv[4];
        #pragma unroll
        for (int e = 0; e < 4; ++e) yv[e] = yp[e];
        const float4* dp = reinterpret_cast<const float4*>(dflt + (size_t)a0 * 4);
        float4 ds[8];
        #pragma unroll
        for (int e = 0; e < 8; ++e) ds[e] = dp[e];
        unsigned wws[8] = {w4a.x, w4a.y, w4a.z, w4a.w, w4b.x, w4b.y, w4b.z, w4b.w};
        float y0s[8] = {yv[0].x, yv[0].z, yv[1].x, yv[1].z, yv[2].x, yv[2].z, yv[3].x, yv[3].z};
        float y1s[8] = {yv[0].y, yv[0].w, yv[1].y, yv[1].w, yv[2].y, yv[2].w, yv[3].y, yv[3].w};
        float vs[8];
        #pragma unroll
        for (int e = 0; e < 8; ++e) {
            unsigned w = wws[e];
            int digit = (int)(w & 0xFFFFu);
            bool flag = (w & 0xC0000000u) != 0u;   // override(bit31) or overlap>=thr(bit30)
            int c = flag ? slab[digit] : 0;
            bool pos = (c == 1);
            float4 bv = sbx[digit];
            float4 dv = ds[e];
            float cw = bv.z - bv.x, ch = bv.w - bv.y;
            float ccx = (bv.x + bv.z) * 0.5f, ccy = (bv.y + bv.w) * 0.5f;
            float l0 = (ccx - dv.x) / (dv.z * 0.1f);
            float l1 = (ccy - dv.y) / (dv.w * 0.1f);
            float l2 = logf(cw / dv.z) * 5.f;
            float l3 = logf(ch / dv.w) * 5.f;
            float4 xv = xs[e];
            float s = 0.f, d, ad;
            d = xv.x - l0; ad = fabsf(d); s += (ad < 1.f) ? 0.5f * d * d : ad - 0.5f;
            d = xv.y - l1; ad = fabsf(d); s += (ad < 1.f) ? 0.5f * d * d : ad - 0.5f;
            d = xv.z - l2; ad = fabsf(d); s += (ad < 1.f) ? 0.5f * d * d : ad - 0.5f;
            d = xv.w - l3; ad = fabsf(d); s += (ad < 1.f) ? 0.5f * d * d : ad - 0.5f;
            float y0 = y0s[e], y1v = y1s[e];
            float mx = fmaxf(y0, y1v);
            float lse = mx + logf(expf(y0 - mx) + expf(y1v - mx));
            float ent = lse - ((c == 0) ? y0 : y1v);
            float v = pos ? 0.f : ent;
            vs[e] = v;
            if (pos) { l_smooth += s; l_pos += ent; l_cnt += 1; }
            atomicAdd(&lh[__float_as_uint(v) >> 21], 1u);
        }
        float4* np = reinterpret_cast<float4*>(negv + i0);
        np[0] = make_float4(vs[0], vs[1], vs[2], vs[3]);
        np[1] = make_float4(vs[4], vs[5], vs[6], vs[7]);
    }
    for (int off = 32; off > 0; off >>= 1) {
        l_smooth += __shfl_down(l_smooth, off, 64);
        l_pos    += __shfl_down(l_pos, off, 64);
        l_cnt    += __shfl_down(l_cnt, off, 64);
    }
    __shared__ float rs[4], rp[4]; __shared__ int rc[4];
    int wv = threadIdx.x >> 6;
    if ((threadIdx.x & 63) == 0) { rs[wv] = l_smooth; rp[wv] = l_pos; rc[wv] = l_cnt; }
    __syncthreads();
    if (threadIdx.x == 0) {
        float ss = rs[0] + rs[1] + rs[2] + rs[3];
        float pp = rp[0] + rp[1] + rp[2] + rp[3];
        int   cc = rc[0] + rc[1] + rc[2] + rc[3];
        if (ss != 0.f) atomicAdd((float*)&scal[2], ss);
        if (pp != 0.f) atomicAdd((float*)&scal[1], pp);
        if (cc)        atomicAdd((int*)&scal[0], cc);
    }
    __syncthreads();
    for (int j = threadIdx.x; j < 2048; j += 256) {
        unsigned h = lh[j];
        if (h) atomicAdd(&hist1[j], h);
    }
}

// ---------------- block-cooperative: find bin containing k-th largest in hist
__device__ __forceinline__ void scan_find(const unsigned* __restrict__ hist, int nbins,
                                          unsigned k, unsigned* ts, unsigned* res) {
    int t = threadIdx.x;
    int per = nbins >> 8;
    unsigned s = 0;
    for (int j = 0; j < per; ++j) s += hist[t * per + j];
    ts[t] = s;
    __syncthreads();
    for (int off = 1; off < 256; off <<= 1) {
        unsigned add = (t >= off) ? ts[t - off] : 0u;
        __syncthreads();
        ts[t] += add;
        __syncthreads();
    }
    unsigned total = ts[255];
    unsigned P = (t == 0) ? 0u : ts[t - 1];
    for (int j = 0; j < per; ++j) {
        unsigned h = hist[t * per + j];
        P += h;
        unsigned above = total - P;
        if (above < k && k <= above + h) { res[0] = (unsigned)(t * per + j); res[1] = k - above; }
    }
    __syncthreads();
}

// ---------------- level-2 refine (scans hist1 inline)
__global__ void __launch_bounds__(256) k_refine2(
        const float* __restrict__ negv, int N, const unsigned* __restrict__ scal,
        const unsigned* __restrict__ hist1, unsigned* __restrict__ hist2) {
    __shared__ unsigned ts[256], res[2], lh[2048];
    scan_find(hist1, 2048, scal[0], ts, res);
    unsigned bin1 = res[0];
    for (int j = threadIdx.x; j < 2048; j += 256) lh[j] = 0u;
    __syncthreads();
    for (int i = (blockIdx.x * 256 + threadIdx.x) * 4; i < N; i += gridDim.x * 1024) {
        float4 v4 = *reinterpret_cast<const float4*>(negv + i);
        unsigned u;
        u = __float_as_uint(v4.x); if ((u >> 21) == bin1) atomicAdd(&lh[(u >> 10) & 0x7FFu], 1u);
        u = __float_as_uint(v4.y); if ((u >> 21) == bin1) atomicAdd(&lh[(u >> 10) & 0x7FFu], 1u);
        u = __float_as_uint(v4.z); if ((u >> 21) == bin1) atomicAdd(&lh[(u >> 10) & 0x7FFu], 1u);
        u = __float_as_uint(v4.w); if ((u >> 21) == bin1) atomicAdd(&lh[(u >> 10) & 0x7FFu], 1u);
    }
    __syncthreads();
    for (int j = threadIdx.x; j < 2048; j += 256) {
        unsigned h = lh[j];
        if (h) atomicAdd(&hist2[j], h);
    }
}

// ---------------- level-3 refine (scans hist1+hist2 inline)
__global__ void __launch_bounds__(256) k_refine3(
        const float* __restrict__ negv, int N, const unsigned* __restrict__ scal,
        const unsigned* __restrict__ hist1, const unsigned* __restrict__ hist2,
        unsigned* __restrict__ hist3) {
    __shared__ unsigned ts[256], res[2], lh[1024];
    scan_find(hist1, 2048, scal[0], ts, res);
    unsigned bin1 = res[0], k1 = res[1];
    scan_find(hist2, 2048, k1, ts, res);
    unsigned prefix = (bin1 << 11) | res[0];
    for (int j = threadIdx.x; j < 1024; j += 256) lh[j] = 0u;
    __syncthreads();
    for (int i = (blockIdx.x * 256 + threadIdx.x) * 4; i < N; i += gridDim.x * 1024) {
        float4 v4 = *reinterpret_cast<const float4*>(negv + i);
        unsigned u;
        u = __float_as_uint(v4.x); if ((u >> 10) == prefix) atomicAdd(&lh[u & 0x3FFu], 1u);
        u = __float_as_uint(v4.y); if ((u >> 10) == prefix) atomicAdd(&lh[u & 0x3FFu], 1u);
        u = __float_as_uint(v4.z); if ((u >> 10) == prefix) atomicAdd(&lh[u & 0x3FFu], 1u);
        u = __float_as_uint(v4.w); if ((u >> 10) == prefix) atomicAdd(&lh[u & 0x3FFu], 1u);
    }
    __syncthreads();
    for (int j = threadIdx.x; j < 1024; j += 256) {
        unsigned h = lh[j];
        if (h) atomicAdd(&hist3[j], h);
    }
}

// ---------------- sum above threshold (scans all hists inline) + last-block finalize
__global__ void __launch_bounds__(256) k_sum(
        const float* __restrict__ negv, int N, unsigned* __restrict__ scal,
        const unsigned* __restrict__ hist1, const unsigned* __restrict__ hist2,
        const unsigned* __restrict__ hist3, float* __restrict__ out) {
    __shared__ unsigned ts[256], res[2];
    scan_find(hist1, 2048, scal[0], ts, res);
    unsigned bin1 = res[0], k1 = res[1];
    scan_find(hist2, 2048, k1, ts, res);
    unsigned bin2 = res[0], k2 = res[1];
    scan_find(hist3, 1024, k2, ts, res);
    unsigned k3 = res[1];
    unsigned tb = (bin1 << 21) | (bin2 << 10) | res[0];
    float s = 0.f;
    for (int i = (blockIdx.x * 256 + threadIdx.x) * 4; i < N; i += gridDim.x * 1024) {
        float4 v4 = *reinterpret_cast<const float4*>(negv + i);
        unsigned u;
        u = __float_as_uint(v4.x); if (u > tb) s += v4.x;
        u = __float_as_uint(v4.y); if (u > tb) s += v4.y;
        u = __float_as_uint(v4.z); if (u > tb) s += v4.z;
        u = __float_as_uint(v4.w); if (u > tb) s += v4.w;
    }
    for (int off = 32; off > 0; off >>= 1) s += __shfl_down(s, off, 64);
    __shared__ float rsum[4];
    __shared__ unsigned isLast;
    int wv = threadIdx.x >> 6;
    if ((threadIdx.x & 63) == 0) rsum[wv] = s;
    __syncthreads();
    if (threadIdx.x == 0) {
        float ss = rsum[0] + rsum[1] + rsum[2] + rsum[3];
        if (ss != 0.f) atomicAdd((float*)&scal[9], ss);
        __threadfence();
        unsigned prev = atomicAdd(&scal[12], 1u);
        isLast = (prev == gridDim.x - 1) ? 1u : 0u;
    }
    __syncthreads();
    if (isLast && threadIdx.x == 0) {
        __threadfence();
        volatile unsigned* vs = scal;
        volatile float* vf = (volatile float*)scal;
        float k = (float)vs[0];
        float t = __uint_as_float(tb);
        float neg_sum = vf[9] + (float)k3 * t;
        float smooth = vf[2] / (k * 4.f);
        float ent = (vf[1] + neg_sum) / k;
        out[0] = smooth + ent;
    }
}

extern "C" void kernel_launch(void* const* d_in, const int* in_sizes, int n_in,
                              void* d_out, int out_size, void* d_ws, size_t ws_size,
                              hipStream_t stream) {
    const float* x      = (const float*)d_in[0];
    const float* y      = (const float*)d_in[1];
    const float* boxes  = (const float*)d_in[2];
    const int*   labels = (const int*)d_in[3];
    const float* dflt   = (const float*)d_in[4];
    float* out = (float*)d_out;

    int A = in_sizes[4] / 4;
    int B = in_sizes[1] / (2 * A);
    int M = in_sizes[3] / B;
    int N = B * A;

    unsigned* ws    = (unsigned*)d_ws;
    unsigned* match = ws;                                       // N u32
    float*    negv  = (float*)(ws + (size_t)N);                 // N f32
    unsigned long long* bestbox = (unsigned long long*)(ws + (size_t)2 * N);  // B*M u64
    unsigned* hist1 = ws + (size_t)2 * N + 2 * B * M;           // 2048
    unsigned* hist2 = hist1 + 2048;                             // 2048
    unsigned* hist3 = hist2 + 2048;                             // 1024
    unsigned* scal  = hist3 + 1024;                             // 16 (incl. done ctr)
    int nzero = 2 * B * M + 2048 + 2048 + 1024 + 16;

    int chunks = (A + 255) / 256;
    k_zero<<<dim3((nzero + 255) / 256), dim3(256), 0, stream>>>(ws + (size_t)2 * N, nzero);
    k_matchboth<<<dim3(B * chunks), dim3(256), 0, stream>>>(boxes, dflt, match, bestbox, B, A, M, chunks);
    k_override<<<dim3((B * M + 255) / 256), dim3(256), 0, stream>>>(bestbox, match, B, A, M);
    k_main<<<dim3(N / 2048), dim3(256), 0, stream>>>(x, y, boxes, labels, dflt, match,
                                                     negv, hist1, scal, A, M, N);
    k_refine2<<<dim3(256), dim3(256), 0, stream>>>(negv, N, scal, hist1, hist2);
    k_refine3<<<dim3(256), dim3(256), 0, stream>>>(negv, N, scal, hist1, hist2, hist3);
    k_sum<<<dim3(256), dim3(256), 0, stream>>>(negv, N, scal, hist1, hist2, hist3, out);
}